// Round 2
// baseline (482.097 us; speedup 1.0000x reference)
//
#include <hip/hip_runtime.h>
#include <stdint.h>
#include <stddef.h>

constexpr int B = 4, P = 48000, C = 64, NY = 496, NX = 432, CMAP = 16;
constexpr int CT   = C + CMAP;                    // 80 output channels
constexpr int GPR  = NX / 4;                      // 108 float4 groups per row
constexpr int TOTAL_GROUPS = B * CT * NY * GPR;   // 17,141,760 (exact /256)

// Pass A: build inverse map cell -> point id (cells unique by construction)
__global__ void scatter_inv_kernel(const int* __restrict__ coords,
                                   int* __restrict__ inv) {
    int p = blockIdx.x * blockDim.x + threadIdx.x;
    if (p >= P) return;
    const int4 cd = ((const int4*)coords)[p];     // (b, 0, y, x)
    inv[(cd.x * NY + cd.z) * NX + cd.w] = p;
}

// Pass B: stream the whole output with 16B float4 stores.
//   c <  64 : gather vox[pid*64+c] where inv >= 0, else 0
//   c >= 64 : transposed map_fm[b, x, y, c-64]
__global__ void __launch_bounds__(256) fill_kernel(
        const float* __restrict__ vox, const float* __restrict__ map,
        const int* __restrict__ inv, float* __restrict__ out) {
    int g = blockIdx.x * 256 + threadIdx.x;
    if (g >= TOTAL_GROUPS) return;
    int x0   = (g % GPR) * 4;
    int rest = g / GPR;
    int y  = rest % NY;
    int bc = rest / NY;
    int c  = bc % CT;
    int b  = bc / CT;

    float4 v = make_float4(0.f, 0.f, 0.f, 0.f);

    if (c < C) {
        if (inv != nullptr) {
            const int4 pid4 = *(const int4*)(inv + (b * NY + y) * NX + x0); // 16B aligned
            // pids are -1 (empty) or >=0; AND keeps sign bit only if ALL empty
            if ((pid4.x & pid4.y & pid4.z & pid4.w) < 0) {
                // all empty: v stays zero (common case, ~94% of cells)
            } else {
                if (pid4.x >= 0) v.x = vox[pid4.x * C + c];
                if (pid4.y >= 0) v.y = vox[pid4.y * C + c];
                if (pid4.z >= 0) v.z = vox[pid4.z * C + c];
                if (pid4.w >= 0) v.w = vox[pid4.w * C + c];
            }
        }
    } else {
        int cm = c - C;
        const float* mp = map + ((size_t)(b * NX + x0) * NY + y) * CMAP + cm;
        v.x = mp[0 * (size_t)(NY * CMAP)];
        v.y = mp[1 * (size_t)(NY * CMAP)];
        v.z = mp[2 * (size_t)(NY * CMAP)];
        v.w = mp[3 * (size_t)(NY * CMAP)];
    }
    *(float4*)(out + (size_t)g * 4) = v;   // 16B coalesced store
}

// Fallback if workspace too small for the inverse map: direct scatter
// (one 64-lane wave per point; lane = channel).
__global__ void scatter_direct_kernel(const float* __restrict__ vox,
                                      const int* __restrict__ coords,
                                      float* __restrict__ out) {
    int p = blockIdx.x;
    int c = threadIdx.x;  // 0..63
    const int4 cd = ((const int4*)coords)[p];
    out[(((size_t)cd.x * CT + c) * NY + cd.z) * NX + cd.w] = vox[p * C + c];
}

extern "C" void kernel_launch(void* const* d_in, const int* in_sizes, int n_in,
                              void* d_out, int out_size, void* d_ws, size_t ws_size,
                              hipStream_t stream) {
    const float* vox    = (const float*)d_in[0];   // (P, 64) float32
    const int*   coords = (const int*)d_in[1];     // (P, 4) int32
    const float* map    = (const float*)d_in[3];   // (B, NX, NY, CMAP) float32
    float* out = (float*)d_out;                    // (B, 80, NY, NX) float32

    const size_t inv_bytes = (size_t)B * NY * NX * sizeof(int);  // 3.43 MB
    int* inv = (ws_size >= inv_bytes) ? (int*)d_ws : nullptr;

    if (inv) {
        hipMemsetAsync(inv, 0xFF, inv_bytes, stream);            // all -1
        scatter_inv_kernel<<<(P + 255) / 256, 256, 0, stream>>>(coords, inv);
    }
    fill_kernel<<<TOTAL_GROUPS / 256, 256, 0, stream>>>(vox, map, inv, out);
    if (!inv) {
        scatter_direct_kernel<<<P, 64, 0, stream>>>(vox, coords, out);
    }
}

// Round 4
// 353.812 us; speedup vs baseline: 1.3626x; 1.3626x over previous
//
#include <hip/hip_runtime.h>
#include <stdint.h>
#include <stddef.h>

typedef __attribute__((ext_vector_type(4))) float f32x4;
typedef __attribute__((ext_vector_type(4))) int   i32x4;

constexpr int B = 4, P = 48000, C = 64, NY = 496, NX = 432, CMAP = 16;
constexpr int CT   = C + CMAP;       // 80 output channels
constexpr int X4   = NX / 4;         // 108 float4 groups per row
constexpr int NIDX = CT * X4;        // 8640 float4 stores per (b,y) row

// Pass A: build inverse map cell -> point id (cells unique by construction)
__global__ void scatter_inv_kernel(const int* __restrict__ coords,
                                   int* __restrict__ inv) {
    int p = blockIdx.x * blockDim.x + threadIdx.x;
    if (p >= P) return;
    const int4 cd = ((const int4*)coords)[p];     // (b, 0, y, x)
    inv[(cd.x * NY + cd.z) * NX + cd.w] = p;
}

// Pass B: one block per (b, y) row; produce ALL 80 channel rows for it.
// inv row + transposed map row staged in LDS once -> every input byte is
// fetched from HBM exactly once device-wide. Output: coalesced nt float4.
__global__ void __launch_bounds__(256) row_fill_kernel(
        const float* __restrict__ vox, const float* __restrict__ map,
        const int* __restrict__ inv, float* __restrict__ out) {
    __shared__ __align__(16) int   inv_s[NX];          // 1.7 KB
    __shared__ __align__(16) float m_s[CMAP][NX];      // 27.6 KB, [cm][x]

    const int by  = blockIdx.x;          // 0 .. B*NY-1
    const int b   = by / NY;
    const int y   = by - b * NY;
    const int tid = threadIdx.x;

    // ---- stage inv row (108 int4, coalesced) ----
    if (inv != nullptr) {
        if (tid < X4)
            ((i32x4*)inv_s)[tid] = ((const i32x4*)(inv + (size_t)by * NX))[tid];
    } else {
        for (int i = tid; i < NX; i += 256) inv_s[i] = -1;
    }

    // ---- stage map row transposed: load float4 (x, cm-quad), scatter to [cm][x] ----
    const f32x4* map4 = (const f32x4*)map;
    for (int i = tid; i < NX * 4; i += 256) {
        int x = i >> 2, q = i & 3;
        f32x4 mv = map4[((size_t)(b * NX + x) * NY + y) * 4 + q];
        m_s[q * 4 + 0][x] = mv.x;
        m_s[q * 4 + 1][x] = mv.y;
        m_s[q * 4 + 2][x] = mv.z;
        m_s[q * 4 + 3][x] = mv.w;
    }
    __syncthreads();

    // ---- write all 80 channel rows, float4-coalesced ----
    const size_t out_base = (size_t)b * CT * NY * NX + (size_t)y * NX;
    for (int idx = tid; idx < NIDX; idx += 256) {
        int c  = idx / X4;
        int x4 = idx - c * X4;
        f32x4 v = (f32x4)0.f;
        if (c < C) {
            i32x4 p4 = ((const i32x4*)inv_s)[x4];
            // all pids -1 (sign bit survives AND) -> row segment is empty (~94%)
            if ((p4.x & p4.y & p4.z & p4.w) >= 0) {
                if (p4.x >= 0) v.x = vox[(size_t)p4.x * C + c];
                if (p4.y >= 0) v.y = vox[(size_t)p4.y * C + c];
                if (p4.z >= 0) v.z = vox[(size_t)p4.z * C + c];
                if (p4.w >= 0) v.w = vox[(size_t)p4.w * C + c];
            }
        } else {
            v = *(const f32x4*)&m_s[c - C][x4 * 4];   // ds_read_b128, conflict-free
        }
        __builtin_nontemporal_store(v,
            (f32x4*)(out + out_base + (size_t)c * (NY * NX) + (size_t)x4 * 4));
    }
}

// Fallback (no workspace): direct scatter after row_fill zero/map pass.
__global__ void scatter_direct_kernel(const float* __restrict__ vox,
                                      const int* __restrict__ coords,
                                      float* __restrict__ out) {
    int p = blockIdx.x;
    int c = threadIdx.x;  // 0..63
    const int4 cd = ((const int4*)coords)[p];
    out[(((size_t)cd.x * CT + c) * NY + cd.z) * NX + cd.w] = vox[(size_t)p * C + c];
}

extern "C" void kernel_launch(void* const* d_in, const int* in_sizes, int n_in,
                              void* d_out, int out_size, void* d_ws, size_t ws_size,
                              hipStream_t stream) {
    const float* vox    = (const float*)d_in[0];   // (P, 64) float32
    const int*   coords = (const int*)d_in[1];     // (P, 4) int32
    const float* map    = (const float*)d_in[3];   // (B, NX, NY, CMAP) float32
    float* out = (float*)d_out;                    // (B, 80, NY, NX) float32

    const size_t inv_bytes = (size_t)B * NY * NX * sizeof(int);  // 3.43 MB
    int* inv = (ws_size >= inv_bytes) ? (int*)d_ws : nullptr;

    if (inv) {
        (void)hipMemsetAsync(inv, 0xFF, inv_bytes, stream);      // all -1
        scatter_inv_kernel<<<(P + 255) / 256, 256, 0, stream>>>(coords, inv);
    }
    row_fill_kernel<<<B * NY, 256, 0, stream>>>(vox, map, inv, out);
    if (!inv) {
        scatter_direct_kernel<<<P, 64, 0, stream>>>(vox, coords, out);
    }
}

// Round 5
// 346.282 us; speedup vs baseline: 1.3922x; 1.0217x over previous
//
#include <hip/hip_runtime.h>
#include <stdint.h>
#include <stddef.h>

typedef __attribute__((ext_vector_type(4))) float f32x4;
typedef __attribute__((ext_vector_type(4))) int   i32x4;

constexpr int B = 4, P = 48000, C = 64, NY = 496, NX = 432, CMAP = 16;
constexpr int CT = C + CMAP;           // 80 output channels
constexpr int X4 = NX / 4;             // 108 float4 groups per row
constexpr int GV = B * C * NY * X4;    // 13,713,408 float4 groups (c<64); /256 = 53568 exact

// Pass A: build inverse map cell -> point id (cells unique by construction)
__global__ void scatter_inv_kernel(const int* __restrict__ coords,
                                   int* __restrict__ inv) {
    int p = blockIdx.x * blockDim.x + threadIdx.x;
    if (p >= P) return;
    const int4 cd = ((const int4*)coords)[p];     // (b, 0, y, x)
    inv[(cd.x * NY + cd.z) * NX + cd.w] = p;
}

// Kernel V: channels 0..63, flat grid, no LDS/barriers. One float4 store per
// thread; inv int4 read is L2-resident (3.4 MB), vox gather rare (~6%) and
// L3-resident (12.3 MB).
__global__ void __launch_bounds__(256) vox_fill_kernel(
        const float* __restrict__ vox, const int* __restrict__ inv,
        float* __restrict__ out) {
    int g = blockIdx.x * 256 + threadIdx.x;       // < GV, exact
    int x4   = g % X4;
    int rest = g / X4;
    int y  = rest % NY;
    int bc = rest / NY;                           // b*64 + c
    int c  = bc & (C - 1);
    int b  = bc >> 6;

    f32x4 v = (f32x4)0.f;
    i32x4 p4 = ((const i32x4*)inv)[(b * NY + y) * X4 + x4];  // coalesced int4
    // pids are -1 (empty) or >=0; AND keeps sign bit only if ALL empty (~94%)
    if ((p4.x & p4.y & p4.z & p4.w) >= 0) {
        if (p4.x >= 0) v.x = vox[(size_t)p4.x * C + c];
        if (p4.y >= 0) v.y = vox[(size_t)p4.y * C + c];
        if (p4.z >= 0) v.z = vox[(size_t)p4.z * C + c];
        if (p4.w >= 0) v.w = vox[(size_t)p4.w * C + c];
    }
    *(f32x4*)(out + (((size_t)b * CT + c) * NY + y) * NX + x4 * 4) = v;
}

// Kernel M: channels 64..79 (map transpose). One block per (b,y) row; stage
// the row's map data [x][16cm] transposed into LDS once (each 64B map line
// fetched exactly once device-wide), then write 16 coalesced channel rows.
__global__ void __launch_bounds__(256) map_fill_kernel(
        const float* __restrict__ map, float* __restrict__ out) {
    __shared__ __align__(16) float m_s[CMAP][NX];  // 27.6 KB, [cm][x]

    const int by  = blockIdx.x;        // 0 .. B*NY-1
    const int b   = by / NY;
    const int y   = by - b * NY;
    const int tid = threadIdx.x;

    const f32x4* map4 = (const f32x4*)map;
    for (int i = tid; i < NX * 4; i += 256) {
        int x = i >> 2, q = i & 3;
        f32x4 mv = map4[((size_t)(b * NX + x) * NY + y) * 4 + q];
        m_s[q * 4 + 0][x] = mv.x;
        m_s[q * 4 + 1][x] = mv.y;
        m_s[q * 4 + 2][x] = mv.z;
        m_s[q * 4 + 3][x] = mv.w;
    }
    __syncthreads();

    const size_t out_base = ((size_t)b * CT + C) * NY * NX + (size_t)y * NX;
    for (int idx = tid; idx < CMAP * X4; idx += 256) {   // 1728, 6.75 iters
        int cm = idx / X4;
        int x4 = idx - cm * X4;
        f32x4 v = *(const f32x4*)&m_s[cm][x4 * 4];       // ds_read_b128
        *(f32x4*)(out + out_base + (size_t)cm * (NY * NX) + (size_t)x4 * 4) = v;
    }
}

// Fallback (no workspace): direct scatter over the zeroed canvas.
__global__ void scatter_direct_kernel(const float* __restrict__ vox,
                                      const int* __restrict__ coords,
                                      float* __restrict__ out) {
    int p = blockIdx.x;
    int c = threadIdx.x;  // 0..63
    const int4 cd = ((const int4*)coords)[p];
    out[(((size_t)cd.x * CT + c) * NY + cd.z) * NX + cd.w] = vox[(size_t)p * C + c];
}

__global__ void zero_vox_region_kernel(float* __restrict__ out) {
    int g = blockIdx.x * 256 + threadIdx.x;
    if (g >= GV) return;
    int x4   = g % X4;
    int rest = g / X4;
    int y  = rest % NY;
    int bc = rest / NY;
    int c  = bc & (C - 1);
    int b  = bc >> 6;
    *(f32x4*)(out + (((size_t)b * CT + c) * NY + y) * NX + x4 * 4) = (f32x4)0.f;
}

extern "C" void kernel_launch(void* const* d_in, const int* in_sizes, int n_in,
                              void* d_out, int out_size, void* d_ws, size_t ws_size,
                              hipStream_t stream) {
    const float* vox    = (const float*)d_in[0];   // (P, 64) float32
    const int*   coords = (const int*)d_in[1];     // (P, 4) int32
    const float* map    = (const float*)d_in[3];   // (B, NX, NY, CMAP) float32
    float* out = (float*)d_out;                    // (B, 80, NY, NX) float32

    const size_t inv_bytes = (size_t)B * NY * NX * sizeof(int);  // 3.43 MB
    int* inv = (ws_size >= inv_bytes) ? (int*)d_ws : nullptr;

    if (inv) {
        (void)hipMemsetAsync(inv, 0xFF, inv_bytes, stream);      // all -1
        scatter_inv_kernel<<<(P + 255) / 256, 256, 0, stream>>>(coords, inv);
        vox_fill_kernel<<<GV / 256, 256, 0, stream>>>(vox, inv, out);
    } else {
        zero_vox_region_kernel<<<GV / 256, 256, 0, stream>>>(out);
        scatter_direct_kernel<<<P, 64, 0, stream>>>(vox, coords, out);
    }
    map_fill_kernel<<<B * NY, 256, 0, stream>>>(map, out);
}

// Round 6
// 335.409 us; speedup vs baseline: 1.4373x; 1.0324x over previous
//
#include <hip/hip_runtime.h>
#include <stdint.h>
#include <stddef.h>

typedef __attribute__((ext_vector_type(4))) float f32x4;
typedef __attribute__((ext_vector_type(4))) int   i32x4;

constexpr int B = 4, P = 48000, C = 64, NY = 496, NX = 432, CMAP = 16;
constexpr int CT  = C + CMAP;          // 80 output channels
constexpr int X4  = NX / 4;            // 108 float4 groups per full row
constexpr int GV  = B * C * NY * X4;   // 13,713,408 vox float4 groups
constexpr int NBV = GV / 256;          // 53,568 vox blocks (exact)
constexpr int XH  = NX / 2;            // 216: half-row for map LDS tile
constexpr int XH4 = XH / 4;            // 54
constexpr int NBM = B * NY * 2;        // 3,968 map blocks (half-rows)

// Pass A: build inverse map cell -> point id (cells unique by construction)
__global__ void scatter_inv_kernel(const int* __restrict__ coords,
                                   int* __restrict__ inv) {
    int p = blockIdx.x * blockDim.x + threadIdx.x;
    if (p >= P) return;
    const int4 cd = ((const int4*)coords)[p];     // (b, 0, y, x)
    inv[(cd.x * NY + cd.z) * NX + cd.w] = p;
}

// Fused fill: blocks [0,NBM) do the map transpose (LDS-staged, fetch-once);
// blocks [NBM, NBM+NBV) do the c<64 inv-gather fill. All output stores are
// nontemporal (write-once stream) to keep inv/vox resident in L2.
__global__ void __launch_bounds__(256) fused_fill_kernel(
        const float* __restrict__ vox, const float* __restrict__ map,
        const int* __restrict__ inv, float* __restrict__ out) {
    __shared__ __align__(16) float m_s[CMAP][XH];   // 13.8 KB

    const int blk = blockIdx.x;
    const int tid = threadIdx.x;

    if (blk < NBM) {
        // ---- map path: half-row (b, y, half) ----
        const int half = blk & 1;
        const int by   = blk >> 1;
        const int b    = by / NY;
        const int y    = by - b * NY;
        const int x0   = half * XH;

        const f32x4* map4 = (const f32x4*)map;
        for (int i = tid; i < XH * 4; i += 256) {     // 864 quad-loads
            int xh = i >> 2, q = i & 3;
            f32x4 mv = map4[((size_t)(b * NX + x0 + xh) * NY + y) * 4 + q];
            m_s[q * 4 + 0][xh] = mv.x;
            m_s[q * 4 + 1][xh] = mv.y;
            m_s[q * 4 + 2][xh] = mv.z;
            m_s[q * 4 + 3][xh] = mv.w;
        }
        __syncthreads();

        const size_t out_base = ((size_t)b * CT + C) * NY * NX
                              + (size_t)y * NX + x0;
        for (int idx = tid; idx < CMAP * XH4; idx += 256) {   // 864 stores
            int cm = idx / XH4;
            int x4 = idx - cm * XH4;
            f32x4 v = *(const f32x4*)&m_s[cm][x4 * 4];        // ds_read_b128
            __builtin_nontemporal_store(v,
                (f32x4*)(out + out_base + (size_t)cm * (NY * NX) + x4 * 4));
        }
    } else {
        // ---- vox path: channels 0..63, flat, no barrier ----
        int g = (blk - NBM) * 256 + tid;              // < GV, exact
        int x4   = g % X4;
        int rest = g / X4;
        int y  = rest % NY;
        int bc = rest / NY;                           // b*64 + c
        int c  = bc & (C - 1);
        int b  = bc >> 6;

        f32x4 v = (f32x4)0.f;
        i32x4 p4 = ((const i32x4*)inv)[(b * NY + y) * X4 + x4];  // L2-resident
        // pids -1 (empty) or >=0; AND keeps sign bit only if ALL empty (~79%)
        if ((p4.x & p4.y & p4.z & p4.w) >= 0) {
            if (p4.x >= 0) v.x = vox[(size_t)p4.x * C + c];
            if (p4.y >= 0) v.y = vox[(size_t)p4.y * C + c];
            if (p4.z >= 0) v.z = vox[(size_t)p4.z * C + c];
            if (p4.w >= 0) v.w = vox[(size_t)p4.w * C + c];
        }
        __builtin_nontemporal_store(v,
            (f32x4*)(out + (((size_t)b * CT + c) * NY + y) * NX + x4 * 4));
    }
}

// Fallback path (no workspace): zero canvas region then direct scatter.
__global__ void zero_vox_region_kernel(float* __restrict__ out) {
    int g = blockIdx.x * 256 + threadIdx.x;
    if (g >= GV) return;
    int x4   = g % X4;
    int rest = g / X4;
    int y  = rest % NY;
    int bc = rest / NY;
    int c  = bc & (C - 1);
    int b  = bc >> 6;
    *(f32x4*)(out + (((size_t)b * CT + c) * NY + y) * NX + x4 * 4) = (f32x4)0.f;
}

__global__ void scatter_direct_kernel(const float* __restrict__ vox,
                                      const int* __restrict__ coords,
                                      float* __restrict__ out) {
    int p = blockIdx.x;
    int c = threadIdx.x;  // 0..63
    const int4 cd = ((const int4*)coords)[p];
    out[(((size_t)cd.x * CT + c) * NY + cd.z) * NX + cd.w] = vox[(size_t)p * C + c];
}

__global__ void map_only_kernel(const float* __restrict__ map,
                                float* __restrict__ out) {
    // fallback map transpose without LDS reuse guarantees (correctness path)
    int g = blockIdx.x * 256 + threadIdx.x;
    if (g >= B * CMAP * NY * NX) return;
    int x    = g % NX;
    int rest = g / NX;
    int y  = rest % NY;
    int bc = rest / NY;
    int cm = bc & (CMAP - 1);
    int b  = bc >> 4;
    out[((size_t)b * CT + C + cm) * NY * NX + (size_t)y * NX + x] =
        map[((size_t)(b * NX + x) * NY + y) * CMAP + cm];
}

extern "C" void kernel_launch(void* const* d_in, const int* in_sizes, int n_in,
                              void* d_out, int out_size, void* d_ws, size_t ws_size,
                              hipStream_t stream) {
    const float* vox    = (const float*)d_in[0];   // (P, 64) float32
    const int*   coords = (const int*)d_in[1];     // (P, 4) int32
    const float* map    = (const float*)d_in[3];   // (B, NX, NY, CMAP) float32
    float* out = (float*)d_out;                    // (B, 80, NY, NX) float32

    const size_t inv_bytes = (size_t)B * NY * NX * sizeof(int);  // 3.43 MB
    int* inv = (ws_size >= inv_bytes) ? (int*)d_ws : nullptr;

    if (inv) {
        (void)hipMemsetAsync(inv, 0xFF, inv_bytes, stream);      // all -1
        scatter_inv_kernel<<<(P + 255) / 256, 256, 0, stream>>>(coords, inv);
        fused_fill_kernel<<<NBM + NBV, 256, 0, stream>>>(vox, map, inv, out);
    } else {
        zero_vox_region_kernel<<<NBV, 256, 0, stream>>>(out);
        scatter_direct_kernel<<<P, 64, 0, stream>>>(vox, coords, out);
        map_only_kernel<<<(B * CMAP * NY * NX + 255) / 256, 256, 0, stream>>>(map, out);
    }
}

// Round 7
// 332.005 us; speedup vs baseline: 1.4521x; 1.0103x over previous
//
#include <hip/hip_runtime.h>
#include <stdint.h>
#include <stddef.h>

typedef __attribute__((ext_vector_type(4))) float f32x4;
typedef __attribute__((ext_vector_type(4))) int   i32x4;

constexpr int B = 4, P = 48000, C = 64, NY = 496, NX = 432, CMAP = 16;
constexpr int CT  = C + CMAP;            // 80 output channels
constexpr int X4  = NX / 4;              // 108 float4 groups per full row
constexpr int CQ  = C / 4;               // 16 channel quads
constexpr int GV2 = B * CQ * NY * X4;    // 3,428,352 threads (vox path)
constexpr int NBV = GV2 / 256;           // 13,392 vox blocks (exact)
constexpr int XH  = NX / 2;              // 216: half-row for map LDS tile
constexpr int XH4 = XH / 4;              // 54
constexpr int NBM = B * NY * 2;          // 3,968 map blocks (half-rows)

// Pass A: build inverse map cell -> point id (cells unique by construction)
__global__ void scatter_inv_kernel(const int* __restrict__ coords,
                                   int* __restrict__ inv) {
    int p = blockIdx.x * blockDim.x + threadIdx.x;
    if (p >= P) return;
    const int4 cd = ((const int4*)coords)[p];     // (b, 0, y, x)
    inv[(cd.x * NY + cd.z) * NX + cd.w] = p;
}

// Fused fill:
//   blocks [0,NBM): map transpose (LDS half-row tiles, fetch-once)
//   blocks [NBM,..): vox path — one thread = one (b,y,x4) group x 4 channels.
//     inv int4 read once per 4 stores; gather = one f32x4/pid + 4x4 register
//     transpose. All stores nontemporal (write-once stream).
__global__ void __launch_bounds__(256) fused_fill_kernel(
        const float* __restrict__ vox, const float* __restrict__ map,
        const int* __restrict__ inv, float* __restrict__ out) {
    __shared__ __align__(16) float m_s[CMAP][XH];   // 13.8 KB

    const int blk = blockIdx.x;
    const int tid = threadIdx.x;

    if (blk < NBM) {
        // ---- map path: half-row (b, y, half) ----
        const int half = blk & 1;
        const int by   = blk >> 1;
        const int b    = by / NY;
        const int y    = by - b * NY;
        const int x0   = half * XH;

        const f32x4* map4 = (const f32x4*)map;
        for (int i = tid; i < XH * 4; i += 256) {     // 864 quad-loads
            int xh = i >> 2, q = i & 3;
            f32x4 mv = map4[((size_t)(b * NX + x0 + xh) * NY + y) * 4 + q];
            m_s[q * 4 + 0][xh] = mv.x;
            m_s[q * 4 + 1][xh] = mv.y;
            m_s[q * 4 + 2][xh] = mv.z;
            m_s[q * 4 + 3][xh] = mv.w;
        }
        __syncthreads();

        const size_t out_base = ((size_t)b * CT + C) * NY * NX
                              + (size_t)y * NX + x0;
        for (int idx = tid; idx < CMAP * XH4; idx += 256) {   // 864 stores
            int cm = idx / XH4;
            int x4 = idx - cm * XH4;
            f32x4 v = *(const f32x4*)&m_s[cm][x4 * 4];        // ds_read_b128
            __builtin_nontemporal_store(v,
                (f32x4*)(out + out_base + (size_t)cm * (NY * NX) + x4 * 4));
        }
    } else {
        // ---- vox path ----
        int g = (blk - NBM) * 256 + tid;              // < GV2, exact
        int x4   = g % X4;
        int rest = g / X4;
        int y   = rest % NY;
        int bcq = rest / NY;                          // b*16 + cq
        int cq  = bcq & (CQ - 1);
        int b   = bcq >> 4;
        int c0  = cq * 4;

        i32x4 p4 = ((const i32x4*)inv)[(b * NY + y) * X4 + x4];

        f32x4 r0 = (f32x4)0.f, r1 = (f32x4)0.f, r2 = (f32x4)0.f, r3 = (f32x4)0.f;
        // pids -1 (empty) or >=0; AND keeps sign bit only if ALL empty (~79%)
        if ((p4.x & p4.y & p4.z & p4.w) >= 0) {
            const f32x4* vox4 = (const f32x4*)vox;    // vox row = 16 f32x4
            if (p4.x >= 0) r0 = vox4[(size_t)p4.x * CQ + cq];
            if (p4.y >= 0) r1 = vox4[(size_t)p4.y * CQ + cq];
            if (p4.z >= 0) r2 = vox4[(size_t)p4.z * CQ + cq];
            if (p4.w >= 0) r3 = vox4[(size_t)p4.w * CQ + cq];
        }

        float* ob = out + (((size_t)b * CT + c0) * NY + y) * NX + x4 * 4;
        const size_t PL = (size_t)NY * NX;            // channel-plane stride
        f32x4 s;
        s.x = r0.x; s.y = r1.x; s.z = r2.x; s.w = r3.x;
        __builtin_nontemporal_store(s, (f32x4*)(ob));
        s.x = r0.y; s.y = r1.y; s.z = r2.y; s.w = r3.y;
        __builtin_nontemporal_store(s, (f32x4*)(ob + PL));
        s.x = r0.z; s.y = r1.z; s.z = r2.z; s.w = r3.z;
        __builtin_nontemporal_store(s, (f32x4*)(ob + 2 * PL));
        s.x = r0.w; s.y = r1.w; s.z = r2.w; s.w = r3.w;
        __builtin_nontemporal_store(s, (f32x4*)(ob + 3 * PL));
    }
}

// Fallback path (no workspace): zero canvas region then direct scatter.
__global__ void zero_vox_region_kernel(float* __restrict__ out) {
    int g = blockIdx.x * 256 + threadIdx.x;
    if (g >= B * C * NY * X4) return;
    int x4   = g % X4;
    int rest = g / X4;
    int y  = rest % NY;
    int bc = rest / NY;
    int c  = bc & (C - 1);
    int b  = bc >> 6;
    *(f32x4*)(out + (((size_t)b * CT + c) * NY + y) * NX + x4 * 4) = (f32x4)0.f;
}

__global__ void scatter_direct_kernel(const float* __restrict__ vox,
                                      const int* __restrict__ coords,
                                      float* __restrict__ out) {
    int p = blockIdx.x;
    int c = threadIdx.x;  // 0..63
    const int4 cd = ((const int4*)coords)[p];
    out[(((size_t)cd.x * CT + c) * NY + cd.z) * NX + cd.w] = vox[(size_t)p * C + c];
}

__global__ void map_only_kernel(const float* __restrict__ map,
                                float* __restrict__ out) {
    int g = blockIdx.x * 256 + threadIdx.x;
    if (g >= B * CMAP * NY * NX) return;
    int x    = g % NX;
    int rest = g / NX;
    int y  = rest % NY;
    int bc = rest / NY;
    int cm = bc & (CMAP - 1);
    int b  = bc >> 4;
    out[((size_t)b * CT + C + cm) * NY * NX + (size_t)y * NX + x] =
        map[((size_t)(b * NX + x) * NY + y) * CMAP + cm];
}

extern "C" void kernel_launch(void* const* d_in, const int* in_sizes, int n_in,
                              void* d_out, int out_size, void* d_ws, size_t ws_size,
                              hipStream_t stream) {
    const float* vox    = (const float*)d_in[0];   // (P, 64) float32
    const int*   coords = (const int*)d_in[1];     // (P, 4) int32
    const float* map    = (const float*)d_in[3];   // (B, NX, NY, CMAP) float32
    float* out = (float*)d_out;                    // (B, 80, NY, NX) float32

    const size_t inv_bytes = (size_t)B * NY * NX * sizeof(int);  // 3.43 MB
    int* inv = (ws_size >= inv_bytes) ? (int*)d_ws : nullptr;

    if (inv) {
        (void)hipMemsetAsync(inv, 0xFF, inv_bytes, stream);      // all -1
        scatter_inv_kernel<<<(P + 255) / 256, 256, 0, stream>>>(coords, inv);
        fused_fill_kernel<<<NBM + NBV, 256, 0, stream>>>(vox, map, inv, out);
    } else {
        zero_vox_region_kernel<<<(B * C * NY * X4 + 255) / 256, 256, 0, stream>>>(out);
        scatter_direct_kernel<<<P, 64, 0, stream>>>(vox, coords, out);
        map_only_kernel<<<(B * CMAP * NY * NX + 255) / 256, 256, 0, stream>>>(map, out);
    }
}